// Round 3
// baseline (233.690 us; speedup 1.0000x reference)
//
#include <hip/hip_runtime.h>
#include <hip/hip_bf16.h>

typedef short short8 __attribute__((ext_vector_type(8)));
typedef float floatx4 __attribute__((ext_vector_type(4)));

#define DEVI __device__ __forceinline__

// Dims: B=4, T=4096, D=256, E=12 (4x k5, 4x k9, 4x k17), 16384 tokens.
// fp32 in/out; MFMA operands bf16.
// fused: 512 blocks x 512 threads (8 waves): waves 0-3 conv producers,
//        waves 4-7 GEMM consumers. BM=32 tokens/block. 2 blocks/CU target.
//
// Workspace: projWT bf16 [12][256f][256d] @0 (1,572,864)
//            outWT  bf16 [256f][256k] @1,572,864 (131,072)
//            rWT    bf16 [16e][256d]  @1,703,936 (8,192)

DEVI float bf2f(__hip_bfloat16 v) { return __bfloat162float(v); }
DEVI __hip_bfloat16 f2bf(float v) { return __float2bfloat16(v); }
DEVI unsigned short bfbits(float v) { __hip_bfloat16 b = f2bf(v); return *(unsigned short*)&b; }
DEVI float lo_of(unsigned int u) { unsigned int t = u << 16; return *(float*)&t; }
DEVI float hi_of(unsigned int u) { unsigned int t = u & 0xffff0000u; return *(float*)&t; }

// ---------------------------------------------------------------- prep ----
// 209 blocks: 0..191 projW 64x64 tiles, 192..207 outW tiles, 208 rW.
__global__ __launch_bounds__(256) void prep_kernel(
    const float* __restrict__ projW,   // [12][256d][256f]
    const float* __restrict__ outW,    // [256k][256f]
    const float* __restrict__ rW,      // [256d][12e]
    __hip_bfloat16* __restrict__ projWT,  // [12][256f][256d]
    __hip_bfloat16* __restrict__ outWT,   // [256f][256k]
    __hip_bfloat16* __restrict__ rWT)     // [16e][256d]
{
    __shared__ __align__(16) __hip_bfloat16 Tt[64 * 72];
    const int tid = threadIdx.x;
    const int bid = blockIdx.x;

    if (bid == 208) {
        for (int e = 0; e < 16; e++)
            rWT[e * 256 + tid] = (e < 12) ? f2bf(rW[tid * 12 + e]) : f2bf(0.0f);
        return;
    }

    const float* src;
    __hip_bfloat16* dst;
    if (bid < 192) {
        int e = bid >> 4, ti = (bid & 15) >> 2, tj = bid & 3;
        src = projW + (e << 16) + (ti * 64) * 256 + tj * 64;   // [r][c]
        dst = projWT + (e << 16) + (tj * 64) * 256 + ti * 64;  // [c][r]
    } else {
        int b2 = bid - 192, ti = b2 >> 2, tj = b2 & 3;
        src = outW + (ti * 64) * 256 + tj * 64;
        dst = outWT + (tj * 64) * 256 + ti * 64;
    }

    // load 64x64 f32 tile, write transposed into LDS as [c][r]
#pragma unroll
    for (int i = 0; i < 4; i++) {
        int r = i * 16 + (tid >> 4);
        int c4 = (tid & 15) * 4;
        float4 f = *(const float4*)(src + r * 256 + c4);
        Tt[(c4 + 0) * 72 + r] = f2bf(f.x);
        Tt[(c4 + 1) * 72 + r] = f2bf(f.y);
        Tt[(c4 + 2) * 72 + r] = f2bf(f.z);
        Tt[(c4 + 3) * 72 + r] = f2bf(f.w);
    }
    __syncthreads();
    // write out [c][r] rows, b128 coalesced
#pragma unroll
    for (int i = 0; i < 2; i++) {
        int c = i * 32 + (tid >> 3);
        int r8 = (tid & 7) * 8;
        *(short8*)(dst + c * 256 + r8) = *(const short8*)(Tt + c * 72 + r8);
    }
}

// --------------------------------------------------------------- fused ----
// LDS (64,000 B):
//   xs     bf16 [48][272] @0      (26,112)
//   As0    bf16 [32][264] @26,112 (16,896)
//   As1    bf16 [32][264] @43,008 (16,896)
//   wts_s  f32  [32][12]  @59,904 (1,536)
//   psum   f32  [32][9]   @61,440   psq @62,592   muA @63,744  rsA @63,872
//   mixed  f32  [32][257] @0 (aliases xs/As0, live after expert loop)
//   normed bf16 [32][264] @43,008 (aliases As1, live after LN)

template<int K>
DEVI void conv_pair(const float* __restrict__ cw,  // [K][256], this expert
                    const __hip_bfloat16* xs, const float* wts_s, int e,
                    __hip_bfloat16* dst, int dp, int tb)
{
    float c0[K], c1[K];
#pragma unroll
    for (int j = 0; j < K; j++) {
        float2 f = *(const float2*)(cw + j * 256 + dp);
        c0[j] = f.x; c1[j] = f.y;
    }
    float w0[K - 1], w1[K - 1];
#pragma unroll
    for (int i = 0; i < K - 1; i++) {
        unsigned int u = *(const unsigned int*)(xs + (16 + tb - (K - 1) + i) * 272 + dp);
        w0[i] = lo_of(u); w1[i] = hi_of(u);
    }
#pragma unroll
    for (int t = 0; t < 16; t++) {
        unsigned int u = *(const unsigned int*)(xs + (16 + tb + t) * 272 + dp);
        float nv0 = lo_of(u), nv1 = hi_of(u);
        float s0 = nv0 * c0[K - 1], s1 = nv1 * c1[K - 1];
#pragma unroll
        for (int i = 0; i < K - 1; i++) { s0 += w0[i] * c0[i]; s1 += w1[i] * c1[i]; }
        float w = wts_s[(tb + t) * 12 + e];
        unsigned int pk = (unsigned int)bfbits(s0 * w) |
                          ((unsigned int)bfbits(s1 * w) << 16);
        *(unsigned int*)(dst + (tb + t) * 264 + dp) = pk;
#pragma unroll
        for (int i = 0; i + 1 < K - 1; i++) { w0[i] = w0[i + 1]; w1[i] = w1[i + 1]; }
        w0[K - 2] = nv0; w1[K - 2] = nv1;
    }
}

DEVI void conv_dispatch(int e,
                        const float* ck5, const float* ck9, const float* ck17,
                        const __hip_bfloat16* xs, const float* wts_s,
                        __hip_bfloat16* dst, int dp, int tb)
{
    if (e < 4)      conv_pair<5>(ck5 + e * 5 * 256, xs, wts_s, e, dst, dp, tb);
    else if (e < 8) conv_pair<9>(ck9 + (e - 4) * 9 * 256, xs, wts_s, e, dst, dp, tb);
    else            conv_pair<17>(ck17 + (e - 8) * 17 * 256, xs, wts_s, e, dst, dp, tb);
}

// M=32 x N=64(slice) x K=256, B prefetch distance 2 (ring-3, <=12 loads in flight)
DEVI void gemm32(const __hip_bfloat16* __restrict__ A,   // LDS [32][264]
                 const __hip_bfloat16* __restrict__ Bg,  // global [256n][256k]
                 floatx4 (&acc)[2][4], int l16, int quad, int nq)
{
    const __hip_bfloat16* a0p = A + l16 * 264 + quad * 8;
    const __hip_bfloat16* a1p = a0p + 16 * 264;
    const __hip_bfloat16* bp  = Bg + (nq * 64 + l16) * 256 + quad * 8;
    short8 br[3][4];
#define LOADB(slot, ks) { const __hip_bfloat16* q = bp + (ks) * 32;          \
        br[slot][0] = *(const short8*)(q);                                    \
        br[slot][1] = *(const short8*)(q + 4096);                             \
        br[slot][2] = *(const short8*)(q + 8192);                             \
        br[slot][3] = *(const short8*)(q + 12288); }
    LOADB(0, 0)
    LOADB(1, 1)
#pragma unroll
    for (int ks = 0; ks < 8; ks++) {
        if (ks < 6) LOADB((ks + 2) % 3, ks + 2)
        short8 a0 = *(const short8*)(a0p + ks * 32);
        short8 a1 = *(const short8*)(a1p + ks * 32);
        const int s = ks % 3;
        acc[0][0] = __builtin_amdgcn_mfma_f32_16x16x32_bf16(a0, br[s][0], acc[0][0], 0, 0, 0);
        acc[0][1] = __builtin_amdgcn_mfma_f32_16x16x32_bf16(a0, br[s][1], acc[0][1], 0, 0, 0);
        acc[0][2] = __builtin_amdgcn_mfma_f32_16x16x32_bf16(a0, br[s][2], acc[0][2], 0, 0, 0);
        acc[0][3] = __builtin_amdgcn_mfma_f32_16x16x32_bf16(a0, br[s][3], acc[0][3], 0, 0, 0);
        acc[1][0] = __builtin_amdgcn_mfma_f32_16x16x32_bf16(a1, br[s][0], acc[1][0], 0, 0, 0);
        acc[1][1] = __builtin_amdgcn_mfma_f32_16x16x32_bf16(a1, br[s][1], acc[1][1], 0, 0, 0);
        acc[1][2] = __builtin_amdgcn_mfma_f32_16x16x32_bf16(a1, br[s][2], acc[1][2], 0, 0, 0);
        acc[1][3] = __builtin_amdgcn_mfma_f32_16x16x32_bf16(a1, br[s][3], acc[1][3], 0, 0, 0);
    }
#undef LOADB
}

__global__ __launch_bounds__(512, 4) void fused_kernel(
    const float* __restrict__ x,
    const float* __restrict__ ck5, const float* __restrict__ ck9,
    const float* __restrict__ ck17,
    const float* __restrict__ projb,   // [12][256]
    const float* __restrict__ rb,      // [12]
    const float* __restrict__ gmm, const float* __restrict__ bta,
    const float* __restrict__ outb,    // [256]
    const __hip_bfloat16* __restrict__ projWT,
    const __hip_bfloat16* __restrict__ outWT,
    const __hip_bfloat16* __restrict__ rWT,
    float* __restrict__ out)
{
    __shared__ __align__(16) char smem[64000];
    __hip_bfloat16* xs  = (__hip_bfloat16*)(smem);
    __hip_bfloat16* As0 = (__hip_bfloat16*)(smem + 26112);
    __hip_bfloat16* As1 = (__hip_bfloat16*)(smem + 43008);
    float* wts_s = (float*)(smem + 59904);
    float* psum  = (float*)(smem + 61440);
    float* psq   = (float*)(smem + 62592);
    float* muA   = (float*)(smem + 63744);
    float* rsA   = (float*)(smem + 63872);
    float* mixed = (float*)(smem);             // [32][257]
    __hip_bfloat16* normed = As1;              // [32][264]

    const int tid  = threadIdx.x;
    const int wave = tid >> 6;
    const int lane = tid & 63;
    const int quad = lane >> 4;
    const int l16  = lane & 15;
    const bool producer = (tid < 256);
    const int nq   = wave - 4;                 // consumer n-quarter
    const int dp   = (tid & 127) * 2;          // producer d-pair
    const int tb   = (tid >> 7) * 16;          // producer t-half (0 or 16), tid<256
    const int m0   = blockIdx.x * 32;
    const int bb   = m0 >> 12;
    const int t0   = m0 & 4095;

    // ---- stage x tile rows t0-16..t0+31, fp32 -> bf16 (all 512 threads) ----
    {
        const float* xb = x + (size_t)bb * 4096 * 256;
        for (int idx = tid; idx < 48 * 64; idx += 512) {
            int row = idx >> 6, c4 = (idx & 63) << 2;
            int gt = t0 - 16 + row;
            unsigned int p0 = 0, p1 = 0;
            if (gt >= 0) {
                float4 f = *(const float4*)(xb + (size_t)gt * 256 + c4);
                p0 = (unsigned int)bfbits(f.x) | ((unsigned int)bfbits(f.y) << 16);
                p1 = (unsigned int)bfbits(f.z) | ((unsigned int)bfbits(f.w) << 16);
            }
            *(unsigned int*)(xs + row * 272 + c4) = p0;
            *(unsigned int*)(xs + row * 272 + c4 + 2) = p1;
        }
    }
    __syncthreads();

    // ---- router (waves 0,1): logits via MFMA, softmax via shuffles ----
    if (wave < 2) {
        floatx4 ra = {0.f, 0.f, 0.f, 0.f};
        const __hip_bfloat16* ap = xs + (16 + wave * 16 + l16) * 272 + quad * 8;
        const __hip_bfloat16* bp = rWT + l16 * 256 + quad * 8;
#pragma unroll
        for (int kk = 0; kk < 256; kk += 32)
            ra = __builtin_amdgcn_mfma_f32_16x16x32_bf16(
                *(const short8*)(ap + kk), *(const short8*)(bp + kk), ra, 0, 0, 0);
        float rbv = (l16 < 12) ? rb[l16] : 0.f;
#pragma unroll
        for (int r = 0; r < 4; r++) {
            float v = (l16 < 12) ? (ra[r] + rbv) : -1e30f;
            float mx = v;
            mx = fmaxf(mx, __shfl_xor(mx, 1));
            mx = fmaxf(mx, __shfl_xor(mx, 2));
            mx = fmaxf(mx, __shfl_xor(mx, 4));
            mx = fmaxf(mx, __shfl_xor(mx, 8));
            float ex = (l16 < 12) ? __expf(v - mx) : 0.f;
            float sm = ex;
            sm += __shfl_xor(sm, 1);
            sm += __shfl_xor(sm, 2);
            sm += __shfl_xor(sm, 4);
            sm += __shfl_xor(sm, 8);
            if (l16 < 12) wts_s[(wave * 16 + quad * 4 + r) * 12 + l16] = ex / sm;
        }
    }
    __syncthreads();

    // ---- expert loop: producers conv(e+1), consumers gemm(e) ----
    floatx4 acc[2][4];
#pragma unroll
    for (int i = 0; i < 2; i++)
#pragma unroll
        for (int j = 0; j < 4; j++) acc[i][j] = {0.f, 0.f, 0.f, 0.f};

    if (producer) conv_dispatch(0, ck5, ck9, ck17, xs, wts_s, As0, dp, tb);
    __syncthreads();
#pragma unroll 1
    for (int e = 0; e < 12; e++) {
        if (producer) {
            if (e < 11)
                conv_dispatch(e + 1, ck5, ck9, ck17, xs, wts_s,
                              ((e + 1) & 1) ? As1 : As0, dp, tb);
        } else {
            gemm32((e & 1) ? As1 : As0, projWT + (e << 16), acc, l16, quad, nq);
        }
        __syncthreads();
    }

    // ---- consumers: mixed = acc + sum_e w_e * proj_b[e] ----
    if (!producer) {
#pragma unroll
        for (int mt = 0; mt < 2; mt++) {
#pragma unroll
            for (int r = 0; r < 4; r++) {
                const int row = mt * 16 + quad * 4 + r;
#pragma unroll
                for (int nt = 0; nt < 4; nt++) {
                    const int col = nq * 64 + nt * 16 + l16;
                    float bias = 0.f;
#pragma unroll
                    for (int e2 = 0; e2 < 12; e2++)
                        bias += wts_s[row * 12 + e2] * projb[(e2 << 8) + col];
                    mixed[row * 257 + col] = acc[mt][nt][r] + bias;
                }
            }
        }
    }
    __syncthreads();

    // ---- LayerNorm stats (threads 0..255) ----
    if (tid < 256) {
        const int row = tid >> 3, part = tid & 7;
        float s = 0.f, s2 = 0.f;
#pragma unroll
        for (int jj = 0; jj < 32; jj++) {
            float v = mixed[row * 257 + part + jj * 8];
            s += v; s2 += v * v;
        }
        psum[row * 9 + part] = s;
        psq[row * 9 + part] = s2;
    }
    __syncthreads();
    if (tid < 32) {
        float s = 0.f, s2 = 0.f;
#pragma unroll
        for (int p = 0; p < 8; p++) { s += psum[tid * 9 + p]; s2 += psq[tid * 9 + p]; }
        float mu = s * 0.00390625f;
        float var = fmaxf(s2 * 0.00390625f - mu * mu, 0.f);
        muA[tid] = mu;
        rsA[tid] = rsqrtf(var + 1e-5f);
    }
    __syncthreads();
    for (int idx = tid; idx < 32 * 256; idx += 512) {
        int row = idx >> 8, col = idx & 255;
        float v = (mixed[row * 257 + col] - muA[row]) * rsA[row]
                  * gmm[col] + bta[col];
        normed[row * 264 + col] = f2bf(v);
    }
    __syncthreads();

    // ---- consumers: out = normed @ out_W + out_b ----
    if (!producer) {
        floatx4 acc2[2][4];
#pragma unroll
        for (int i = 0; i < 2; i++)
#pragma unroll
            for (int j = 0; j < 4; j++) acc2[i][j] = {0.f, 0.f, 0.f, 0.f};
        gemm32(normed, outWT, acc2, l16, quad, nq);
        float* ob = out + (size_t)m0 * 256;
#pragma unroll
        for (int mt = 0; mt < 2; mt++) {
#pragma unroll
            for (int r = 0; r < 4; r++) {
                const int row = mt * 16 + quad * 4 + r;
#pragma unroll
                for (int nt = 0; nt < 4; nt++) {
                    const int col = nq * 64 + nt * 16 + l16;
                    ob[row * 256 + col] = acc2[mt][nt][r] + outb[col];
                }
            }
        }
    }
}

// -------------------------------------------------------------- launch ----
extern "C" void kernel_launch(void* const* d_in, const int* in_sizes, int n_in,
                              void* d_out, int out_size, void* d_ws, size_t ws_size,
                              hipStream_t stream)
{
    (void)in_sizes; (void)n_in; (void)out_size; (void)ws_size;
    const float* x     = (const float*)d_in[0];
    const float* ck5   = (const float*)d_in[1];
    const float* ck9   = (const float*)d_in[2];
    const float* ck17  = (const float*)d_in[3];
    const float* projW = (const float*)d_in[4];
    const float* projb = (const float*)d_in[5];
    const float* rW    = (const float*)d_in[6];
    const float* rb    = (const float*)d_in[7];
    const float* outW  = (const float*)d_in[8];
    const float* outb  = (const float*)d_in[9];
    const float* gmm   = (const float*)d_in[10];
    const float* bta   = (const float*)d_in[11];

    __hip_bfloat16* projWT = (__hip_bfloat16*)d_ws;
    __hip_bfloat16* outWT  = (__hip_bfloat16*)((char*)d_ws + 1572864);
    __hip_bfloat16* rWT    = (__hip_bfloat16*)((char*)d_ws + 1703936);

    prep_kernel<<<dim3(209), dim3(256), 0, stream>>>(projW, outW, rW,
                                                     projWT, outWT, rWT);
    fused_kernel<<<dim3(512), dim3(512), 0, stream>>>(
        x, ck5, ck9, ck17, projb, rb, gmm, bta, outb,
        projWT, outWT, rWT, (float*)d_out);
}